// Round 6
// baseline (364.052 us; speedup 1.0000x reference)
//
#include <hip/hip_runtime.h>

#define NN 1024
#define MM 1022          // interior size
#define PS 1024          // padded col stride for ws q0 buffer
#define BB 8
#define TI 64            // trapezoid tile size (rows x cols of data)
#define SL 72            // LDS row stride: 4 left guard + 64 data + 4 right guard
#define RRF 8            // fallback rows/thread

// coef[0..8] = mu*(k1+k2)/(mu*sum(k3)) ; coef[9] = H^2/(mu*sum(k3))
__global__ void coef_kernel(const float* __restrict__ mu,
                            const float* __restrict__ k1,
                            const float* __restrict__ k2,
                            const float* __restrict__ k3,
                            float* __restrict__ coef) {
    if (threadIdx.x == 0 && blockIdx.x == 0) {
        float m = mu[0];
        float s3 = 0.0f;
        for (int t = 0; t < 9; ++t) s3 += k3[t];
        float inv_d = 1.0f / (m * s3);
        for (int t = 0; t < 9; ++t) coef[t] = m * (k1[t] + k2[t]) * inv_d;
        const float h = 1.0f / (float)(NN - 1);
        coef[9] = h * h * inv_d;
    }
}

// Overlapped-tile fused T-step Jacobi, single LDS buffer.
// Data col d lives at LDS word row*SL + 4 + d; words [0,4) and [68,72) are
// zero guards. All window reads are 3x ds_read_b128 (bank-uniform, zero
// conflicts). Per step: read windows -> regs, compute 4x4 acc, barrier,
// in-place write rows 1..62, barrier. Out-of-image cells are NEVER written
// (exact Dirichlet), so no mask registers; interior tiles use a uniform
// fast-path b128 store.
template <int T, bool IN_PAD, bool OUT_PAD>
__global__ __launch_bounds__(256, 6) void trap_kernel(
        const float* __restrict__ yin, const float* __restrict__ f,
        const float* __restrict__ coef, float* __restrict__ yout) {
    constexpr int OUT = TI - 2 * T;
    __shared__ float buf[TI * SL];

    const int t   = threadIdx.x;
    const int b   = blockIdx.z;
    const int o0r = blockIdx.y * OUT - T;   // tile origin, interior coords
    const int o0c = blockIdx.x * OUT - T;

    float c[10];
#pragma unroll
    for (int k = 0; k < 10; ++k) c[k] = coef[k];

    // ---- load phase (lane-contiguous cols -> coalesced) ----
    {
        const int lcol = t & 63;
        const int w    = t >> 6;            // 0..3
        const int gc   = o0c + lcol;
        const bool cok = (gc >= 0) && (gc < MM);
#pragma unroll
        for (int e = 0; e < 16; ++e) {
            const int lrow = e * 4 + w;
            const int gr = o0r + lrow;
            float v = 0.f;
            if (cok && gr >= 0 && gr < MM) {
                v = IN_PAD ? yin[((size_t)b * MM + gr) * PS + gc]
                           : yin[((size_t)b * MM + gr) * MM + gc];
            }
            buf[lrow * SL + 4 + lcol] = v;
        }
        // zero both guard bands: 64 rows x 8 guard cols = 512 cells, 2/thread
#pragma unroll
        for (int g = 0; g < 2; ++g) {
            const int idx = t + g * 256;
            const int row = idx >> 3, wi = idx & 7;
            const int col = (wi < 4) ? wi : 64 + wi;   // 0..3 or 68..71
            buf[row * SL + col] = 0.f;
        }
    }

    // ---- per-thread force registers (includes c9; 0 outside image) ----
    const int cg = t & 15, rg = t >> 4;
    const int lc0 = cg * 4, lr0 = rg * 4;
    float fr[4][4];
#pragma unroll
    for (int r = 0; r < 4; ++r) {
        const int gr = o0r + lr0 + r;
#pragma unroll
        for (int cc = 0; cc < 4; ++cc) {
            const int gc = o0c + lc0 + cc;
            const bool ok = (gr >= 0) && (gr < MM) && (gc >= 0) && (gc < MM);
            fr[r][cc] = ok ? c[9] * f[((size_t)b * NN + (gr + 1)) * NN + (gc + 1)]
                           : 0.f;
        }
    }

    // tile writes any out-of-image cell?  (step writes: rows o0r+1..o0r+62,
    // cols o0c..o0c+63)
    const bool border = (o0r < -1) || (o0r > MM - (TI - 1)) ||
                        (o0c < 0)  || (o0c > MM - TI);

    __syncthreads();

    // ---- T fused steps, 2 barriers each, zero bank conflicts ----
#pragma unroll
    for (int s = 1; s <= T; ++s) {
        float w0[6], w1[6], w2[6];
        auto rd3 = [&](int row, float* wv) {
            const float* rp = buf + row * SL + lc0;
            float4 lq = *(const float4*)(rp);       // data cols lc0-4..lc0-1 (or guard)
            float4 mq = *(const float4*)(rp + 4);   // data cols lc0..lc0+3
            float4 rq = *(const float4*)(rp + 8);   // data cols lc0+4..lc0+7 (or guard)
            wv[0] = lq.w;
            wv[1] = mq.x; wv[2] = mq.y; wv[3] = mq.z; wv[4] = mq.w;
            wv[5] = rq.x;
        };
        rd3((lr0 == 0) ? 0 : lr0 - 1, w0);
        rd3(lr0, w1);

        float acc[4][4];
#pragma unroll
        for (int r = 0; r < 4; ++r) {
            const int lrow = lr0 + r;
            rd3(min(lrow + 1, TI - 1), w2);
#pragma unroll
            for (int cc = 0; cc < 4; ++cc) {
                acc[r][cc] = fr[r][cc]
                    + c[0] * w0[cc] + c[1] * w0[cc + 1] + c[2] * w0[cc + 2]
                    + c[3] * w1[cc] + c[4] * w1[cc + 1] + c[5] * w1[cc + 2]
                    + c[6] * w2[cc] + c[7] * w2[cc + 1] + c[8] * w2[cc + 2];
            }
#pragma unroll
            for (int k = 0; k < 6; ++k) { w0[k] = w1[k]; w1[k] = w2[k]; }
        }

        __syncthreads();

        if (!border) {
#pragma unroll
            for (int r = 0; r < 4; ++r) {
                const int lrow = lr0 + r;
                if (lrow >= 1 && lrow <= TI - 2) {
                    *(float4*)(buf + lrow * SL + 4 + lc0) =
                        make_float4(acc[r][0], acc[r][1], acc[r][2], acc[r][3]);
                }
            }
        } else {
#pragma unroll
            for (int r = 0; r < 4; ++r) {
                const int lrow = lr0 + r;
                const int gr = o0r + lrow;
                if (lrow >= 1 && lrow <= TI - 2 && gr >= 0 && gr < MM) {
#pragma unroll
                    for (int cc = 0; cc < 4; ++cc) {
                        const int gc = o0c + lc0 + cc;
                        if (gc >= 0 && gc < MM)
                            buf[lrow * SL + 4 + lc0 + cc] = acc[r][cc];
                    }
                }
            }
        }

        __syncthreads();
    }

    // ---- store central OUT^2 (lane-contiguous cols -> coalesced) ----
    {
        const int lcol = t & 63;
        const int w    = t >> 6;
        const int oc   = o0c + lcol;
        if (lcol >= T && lcol < T + OUT && oc < MM) {
#pragma unroll
            for (int e = 0; e < 16; ++e) {
                const int lrow = e * 4 + w;
                const int orow = o0r + lrow;
                if (lrow >= T && lrow < T + OUT && orow < MM) {
                    const float v = buf[lrow * SL + 4 + lcol];
                    if (OUT_PAD) yout[((size_t)b * MM + orow) * PS + oc] = v;
                    else         yout[((size_t)b * MM + orow) * MM + oc] = v;
                }
            }
        }
    }
}

// ---------- fallback (round-2 proven path, used if ws too small) ----------
__global__ __launch_bounds__(256) void stencil_kernel(
        const float* __restrict__ yin, const float* __restrict__ f,
        const float* __restrict__ coef, float* __restrict__ yout) {
    const int tid = threadIdx.x;
    const int j0  = tid * 4;
    const int i0  = blockIdx.x * RRF;
    const int b   = blockIdx.y;
    const bool eL = (tid == 0), eR = (tid == 255);

    const float* yb = yin + (size_t)b * MM * MM;
    const float* fb = f   + (size_t)b * NN * NN;

    float c[10];
#pragma unroll
    for (int t = 0; t < 10; ++t) c[t] = coef[t];

    float wP[6], wC[6], wN[6];
    auto loadwin = [&](int r, float* w) {
        if (r < 0 || r >= MM) {
#pragma unroll
            for (int k = 0; k < 6; ++k) w[k] = 0.0f;
            return;
        }
        const float* row = yb + (size_t)r * MM;
        if (eR) {
            float2 ab = *(const float2*)(row + j0);
            w[0] = row[j0 - 1];
            w[1] = ab.x; w[2] = ab.y;
            w[3] = 0.0f; w[4] = 0.0f; w[5] = 0.0f;
        } else {
            float2 ab = *(const float2*)(row + j0);
            float2 cd = *(const float2*)(row + j0 + 2);
            w[0] = eL ? 0.0f : row[j0 - 1];
            w[1] = ab.x; w[2] = ab.y; w[3] = cd.x; w[4] = cd.y;
            w[5] = row[j0 + 4];
        }
    };

    loadwin(i0 - 1, wP);
    loadwin(i0,     wC);

#pragma unroll
    for (int rr = 0; rr < RRF; ++rr) {
        const int i = i0 + rr;
        if (i < MM) {
            loadwin(i + 1, wN);
            const float* frow = fb + (size_t)(i + 1) * NN;
            float fv[4];
            fv[0] = frow[j0 + 1];
            float2 fm = *(const float2*)(frow + j0 + 2);
            fv[1] = fm.x; fv[2] = fm.y;
            fv[3] = frow[j0 + 4];
            float acc[4];
#pragma unroll
            for (int k = 0; k < 4; ++k) acc[k] = c[9] * fv[k];
#pragma unroll
            for (int k = 0; k < 4; ++k) {
                acc[k] += c[0] * wP[k] + c[1] * wP[k + 1] + c[2] * wP[k + 2];
                acc[k] += c[3] * wC[k] + c[4] * wC[k + 1] + c[5] * wC[k + 2];
                acc[k] += c[6] * wN[k] + c[7] * wN[k + 1] + c[8] * wN[k + 2];
            }
            float* orow = (yout + (size_t)b * MM * MM) + (size_t)i * MM + j0;
            *(float2*)orow = make_float2(acc[0], acc[1]);
            if (!eR) *(float2*)(orow + 2) = make_float2(acc[2], acc[3]);
#pragma unroll
            for (int k = 0; k < 6; ++k) { wP[k] = wC[k]; wC[k] = wN[k]; }
        }
    }
}

extern "C" void kernel_launch(void* const* d_in, const int* in_sizes, int n_in,
                              void* d_out, int out_size, void* d_ws, size_t ws_size,
                              hipStream_t stream) {
    const float* pre = (const float*)d_in[1];
    const float* f   = (const float*)d_in[2];
    const float* mu  = (const float*)d_in[3];
    const float* k1  = (const float*)d_in[4];
    const float* k2  = (const float*)d_in[5];
    const float* k3  = (const float*)d_in[6];
    float* out = (float*)d_out;

    float* coef = (float*)d_ws;
    const size_t QE = (size_t)BB * MM * PS;               // intermediate buffer
    const size_t need = 256 + QE * sizeof(float);         // ~33.5 MB

    coef_kernel<<<1, 64, 0, stream>>>(mu, k1, k2, k3, coef);

    if (ws_size >= need) {
        float* q0 = (float*)((char*)d_ws + 256);

        // pass 1: T=6, OUT=52 -> q0 holds y_6 (padded-stride layout)
        {
            constexpr int T = 6, OUTW = TI - 2 * T;       // 52
            const int nt = (MM + OUTW - 1) / OUTW;        // 20
            trap_kernel<T, false, true>
                <<<dim3(nt, nt, BB), 256, 0, stream>>>(pre, f, coef, q0);
        }
        // pass 2: T=5, OUT=54 -> out holds y_11
        {
            constexpr int T = 5, OUTW = TI - 2 * T;       // 54
            const int nt = (MM + OUTW - 1) / OUTW;        // 19
            trap_kernel<T, true, false>
                <<<dim3(nt, nt, BB), 256, 0, stream>>>(q0, f, coef, out);
        }
    } else {
        // fallback: round-2 proven path
        float* buf = (float*)((char*)d_ws + 256);
        dim3 grid((MM + RRF - 1) / RRF, BB);
        const float* in = pre;
        for (int t = 0; t < 11; ++t) {
            float* o = ((t & 1) == 0) ? out : buf;
            stencil_kernel<<<grid, 256, 0, stream>>>(in, f, coef, o);
            in = o;
        }
    }
}